// Round 9
// baseline (347.527 us; speedup 1.0000x reference)
//
#include <hip/hip_runtime.h>

#define B_   64
#define E_   1024
#define N_   512
#define D_   64
#define HID_ 128
#define T_   5

typedef __bf16 bf16x8 __attribute__((ext_vector_type(8)));
typedef float f32x4 __attribute__((ext_vector_type(4)));

__device__ __forceinline__ unsigned short f2bu(float f) {
    union { float f; unsigned int u; } v; v.f = f;
    unsigned int r = (v.u + 0x7fffu + ((v.u >> 16) & 1u)) >> 16;  // RNE
    return (unsigned short)r;
}

__device__ __forceinline__ unsigned int pack2(float lo, float hi) {
    union { __bf16 b[2]; unsigned int u; } v;
    v.b[0] = (__bf16)lo; v.b[1] = (__bf16)hi;   // RNE
    return v.u;
}

__device__ __forceinline__ uint4 cvt8(float4 a, float4 b) {
    union { __bf16 h[8]; uint4 u; } v;
    v.h[0] = (__bf16)a.x; v.h[1] = (__bf16)a.y; v.h[2] = (__bf16)a.z; v.h[3] = (__bf16)a.w;
    v.h[4] = (__bf16)b.x; v.h[5] = (__bf16)b.y; v.h[6] = (__bf16)b.z; v.h[7] = (__bf16)b.w;
    return v.u;
}

#define MFMA16(a, b, c) __builtin_amdgcn_mfma_f32_16x16x32_bf16((a), (b), (c), 0, 0, 0)

// ---------------------------------------------------------------------------
// Prep: W1[t][d][h] -> W1T[t][h][d] bf16 ; W2[t][h][d] -> W2T[t][d][h] bf16
// ---------------------------------------------------------------------------
__global__ __launch_bounds__(256) void k_prep_w(const float* __restrict__ W1,
                                                const float* __restrict__ W2,
                                                unsigned short* __restrict__ W1T,
                                                unsigned short* __restrict__ W2T) {
    int idx = blockIdx.x * 256 + threadIdx.x;
    if (idx < T_ * HID_ * D_) {
        int t = idx / (HID_ * D_), rem = idx % (HID_ * D_);
        int h = rem / D_, d = rem % D_;
        W1T[idx] = f2bu(W1[(t * D_ + d) * HID_ + h]);
    } else {
        int j = idx - T_ * HID_ * D_;
        int t = j / (D_ * HID_), rem = j % (D_ * HID_);
        int d = rem / HID_, h = rem % HID_;
        W2T[j] = f2bu(W2[(t * HID_ + h) * D_ + d]);
    }
}

// ---------------------------------------------------------------------------
// Prep: ori[b][n][d] -> oriT[b][d][n] bf16, and out[b][n][64+d] = ori (fp32)
// grid (8, 64): x = n-tile of 64, y = b
// ---------------------------------------------------------------------------
__global__ __launch_bounds__(256) void k_ori_prep(const float* __restrict__ ori,
                                                  float* __restrict__ out,
                                                  unsigned short* __restrict__ oriT) {
    int b = blockIdx.y, n0 = blockIdx.x * 64;
    __shared__ float tl[64 * 65];
    int tid = threadIdx.x;
    int dl = tid & 63;
    #pragma unroll 4
    for (int p = 0; p < 16; ++p) {
        int nn = p * 4 + (tid >> 6);
        float v = ori[(size_t)(b * N_ + n0 + nn) * D_ + dl];
        out[(size_t)(b * N_ + n0 + nn) * 128 + 64 + dl] = v;
        tl[dl * 65 + nn] = v;
    }
    __syncthreads();
    #pragma unroll 4
    for (int p = 0; p < 16; ++p) {
        int dd = p * 4 + (tid >> 6);
        oriT[(size_t)(b * D_ + dd) * N_ + n0 + dl] = f2bu(tl[dd * 65 + dl]);
    }
}

// ---------------------------------------------------------------------------
// Fused K1+K2 v2: LDS aliased (phase-1 staging shares w_sh; 68.6->49 KB, 3
// blocks/CU) + register-prefetch pipelines (H/oriT across MFMA in phase 1;
// W1T[t+1]/W2T[t] across the opposing GEMM in phase 2). Barrier structure
// and all MFMA/fragment indexing identical to verified R8 kernel.
// grid 1024: b = bx>>4, e0 = (bx&15)*64. 256 threads = 4 waves.
// ---------------------------------------------------------------------------
__global__ __launch_bounds__(256) void k_edge_mlp(const float* __restrict__ H,
                                                  const unsigned short* __restrict__ oriT,
                                                  const float* __restrict__ ed,
                                                  const float* __restrict__ b1,
                                                  const float* __restrict__ b2,
                                                  const unsigned short* __restrict__ W1T,
                                                  const unsigned short* __restrict__ W2T,
                                                  unsigned short* __restrict__ efT) {
    int bx = blockIdx.x;
    int b = bx >> 4, e0 = (bx & 15) * 64;
    __shared__ __align__(16) unsigned short lds[22528];
    unsigned short* w_sh = lds;            // 9216 shorts; phase1: aA|bB alias
    unsigned short* a_sh = lds + 9216;     // 4608 shorts: edges tile [r][d]
    unsigned short* h_sh = lds + 13824;    // 8704 shorts: h' tile [r][hid]
    __shared__ float wd_sh[320];
    __shared__ float b1_sh[640];
    __shared__ float b2_sh[320];
    int tid = threadIdx.x, w = tid >> 6, l = tid & 63, q = l >> 4, c = l & 15;
    int rA = tid >> 3, sgA = tid & 7;      // 8-per-row staging coords
    int rA2 = tid >> 4, sgA2 = tid & 15;   // 16-per-row staging coords

    unsigned short* aA = w_sh;             // 64*72 shorts
    unsigned short* bB = w_sh + 4608;      // 64*72 shorts

    for (int u = tid; u < 320; u += 256) wd_sh[u] = ed[((size_t)b * E_ + e0) * T_ + u];
    for (int u = tid; u < 640; u += 256) b1_sh[u] = b1[u];
    for (int u = tid; u < 320; u += 256) b2_sh[u] = b2[u];

    const f32x4 zero = {0.f, 0.f, 0.f, 0.f};

    // W1T[0] reg-prefetch (consumed at t=0 B0; latency hidden behind phase 1)
    uint4 w1r[4];
    #pragma unroll
    for (int p = 0; p < 4; ++p)
        w1r[p] = *(const uint4*)&W1T[(size_t)(0 * HID_ + p * 32 + rA) * D_ + sgA * 8];

    // ---- Phase 1: edges tile GEMM, reg-prefetch pipeline ----
    float4 hA0[2], hA1[2];
    uint4 oB[2];
    #pragma unroll
    for (int p = 0; p < 2; ++p) {
        const float* s = &H[((size_t)b * E_ + e0 + p * 32 + rA) * N_ + sgA * 8];
        hA0[p] = *(const float4*)&s[0];
        hA1[p] = *(const float4*)&s[4];
        oB[p] = *(const uint4*)&oriT[((size_t)b * D_ + p * 32 + rA) * N_ + sgA * 8];
    }

    f32x4 acc1[4];
    #pragma unroll
    for (int fn = 0; fn < 4; ++fn) acc1[fn] = zero;

    for (int ks = 0; ks < 8; ++ks) {
        #pragma unroll
        for (int p = 0; p < 2; ++p) {
            *(uint4*)&aA[(p * 32 + rA) * 72 + sgA * 8] = cvt8(hA0[p], hA1[p]);
            *(uint4*)&bB[(p * 32 + rA) * 72 + sgA * 8] = oB[p];
        }
        __syncthreads();
        if (ks < 7) {  // issue next step's loads; they fly across MFMA+barrier
            int k0 = (ks + 1) * 64;
            #pragma unroll
            for (int p = 0; p < 2; ++p) {
                const float* s = &H[((size_t)b * E_ + e0 + p * 32 + rA) * N_ + k0 + sgA * 8];
                hA0[p] = *(const float4*)&s[0];
                hA1[p] = *(const float4*)&s[4];
                oB[p] = *(const uint4*)&oriT[((size_t)b * D_ + p * 32 + rA) * N_ + k0 + sgA * 8];
            }
        }
        #pragma unroll
        for (int h = 0; h < 2; ++h) {
            bf16x8 a0 = *(const bf16x8*)&aA[(w * 16 + c) * 72 + h * 32 + q * 8];
            #pragma unroll
            for (int fn = 0; fn < 4; ++fn) {
                bf16x8 bb = *(const bf16x8*)&bB[(fn * 16 + c) * 72 + h * 32 + q * 8];
                acc1[fn] = MFMA16(a0, bb, acc1[fn]);
            }
        }
        __syncthreads();
    }
    // C-layout -> a_sh[r][d] (bf16), same quantization point as before
    #pragma unroll
    for (int fn = 0; fn < 4; ++fn)
        #pragma unroll
        for (int i = 0; i < 4; ++i)
            a_sh[(w * 16 + q * 4 + i) * 72 + fn * 16 + c] = f2bu(acc1[fn][i]);

    // ---- Phase 2: per-type MLP + mixture, weight reg-prefetch ----
    f32x4 y[4];
    #pragma unroll
    for (int fn = 0; fn < 4; ++fn) y[fn] = zero;

    for (int t = 0; t < T_; ++t) {
        __syncthreads();  // B0: prev GEMM2 / phase-1 done with w_sh region
        #pragma unroll
        for (int p = 0; p < 4; ++p)
            *(uint4*)&w_sh[(p * 32 + rA) * 72 + sgA * 8] = w1r[p];
        uint4 w2r[4];     // W2T[t] flies across GEMM1
        #pragma unroll
        for (int p = 0; p < 4; ++p)
            w2r[p] = *(const uint4*)&W2T[(size_t)(t * D_ + p * 16 + rA2) * HID_ + sgA2 * 8];
        __syncthreads();  // B1
        f32x4 hc[8];
        #pragma unroll
        for (int fn = 0; fn < 8; ++fn) hc[fn] = zero;
        #pragma unroll
        for (int ks = 0; ks < 2; ++ks) {
            bf16x8 a = *(const bf16x8*)&a_sh[(w * 16 + c) * 72 + ks * 32 + q * 8];
            #pragma unroll
            for (int fn = 0; fn < 8; ++fn) {
                bf16x8 bb = *(const bf16x8*)&w_sh[(fn * 16 + c) * 72 + ks * 32 + q * 8];
                hc[fn] = MFMA16(a, bb, hc[fn]);
            }
        }
        float wv[4];
        #pragma unroll
        for (int i = 0; i < 4; ++i) wv[i] = wd_sh[(w * 16 + q * 4 + i) * T_ + t];
        #pragma unroll
        for (int fn = 0; fn < 8; ++fn) {
            float b1v = b1_sh[t * HID_ + fn * 16 + c];
            #pragma unroll
            for (int i = 0; i < 4; ++i) {
                float v = hc[fn][i] + b1v;
                v = fmaxf(v, 0.0f) * wv[i];
                h_sh[(w * 16 + q * 4 + i) * 136 + fn * 16 + c] = f2bu(v);
            }
        }
        __syncthreads();  // B2: GEMM1 w_sh reads + h_sh writes complete
        #pragma unroll
        for (int p = 0; p < 4; ++p)
            *(uint4*)&w_sh[(p * 16 + rA2) * 136 + sgA2 * 8] = w2r[p];
        if (t < 4) {      // W1T[t+1] flies across GEMM2
            #pragma unroll
            for (int p = 0; p < 4; ++p)
                w1r[p] = *(const uint4*)&W1T[(size_t)((t + 1) * HID_ + p * 32 + rA) * D_ + sgA * 8];
        }
        __syncthreads();  // B3
        #pragma unroll
        for (int ks = 0; ks < 4; ++ks) {
            bf16x8 a = *(const bf16x8*)&h_sh[(w * 16 + c) * 136 + ks * 32 + q * 8];
            #pragma unroll
            for (int fn = 0; fn < 4; ++fn) {
                bf16x8 bb = *(const bf16x8*)&w_sh[(fn * 16 + c) * 136 + ks * 32 + q * 8];
                y[fn] = MFMA16(a, bb, y[fn]);
            }
        }
    }
    // epilogue: + sum_t w*b2, write efT[b][d][e] transposed (bf16 ushort4)
    #pragma unroll
    for (int fn = 0; fn < 4; ++fn) {
        int d = fn * 16 + c;
        ushort4 o;
        #pragma unroll
        for (int i = 0; i < 4; ++i) {
            int r = w * 16 + q * 4 + i;
            float s = y[fn][i];
            #pragma unroll
            for (int t = 0; t < T_; ++t) s += wd_sh[r * T_ + t] * b2_sh[t * D_ + d];
            ((unsigned short*)&o)[i] = f2bu(s);
        }
        *(ushort4*)&efT[((size_t)b * D_ + d) * E_ + e0 + w * 16 + q * 4] = o;
    }
}

// ---------------------------------------------------------------------------
// K3 v2: same math/layout as verified R7/R8 kernel + reg-prefetch pipeline.
// outT tile: M = d (64), N = n-tile 64, K = e (1024), BK=64. grid (8, 64).
// ---------------------------------------------------------------------------
__global__ __launch_bounds__(256) void k_gemm_out(const float* __restrict__ H,
                                                  const unsigned short* __restrict__ efT,
                                                  float* __restrict__ out) {
    int b = blockIdx.y, n0 = blockIdx.x * 64;
    __shared__ __align__(16) unsigned short aA[64 * 72];   // efT [d][e]
    __shared__ unsigned int bB32[64 * 33];                 // H^T [n][e/2] pair-packed
    int tid = threadIdx.x, w = tid >> 6, l = tid & 63, q = l >> 4, c = l & 15;
    int r2 = tid >> 3, cg = tid & 7;                       // staging coords
    const f32x4 zero = {0.f, 0.f, 0.f, 0.f};
    f32x4 acc[4];
    #pragma unroll
    for (int fm = 0; fm < 4; ++fm) acc[fm] = zero;

    // prefetch ks=0
    uint4 aR[2];
    float4 f0, f1, g0, g1;
    #pragma unroll
    for (int p = 0; p < 2; ++p)
        aR[p] = *(const uint4*)&efT[((size_t)b * D_ + p * 32 + r2) * E_ + cg * 8];
    {
        const float* s0 = &H[((size_t)b * E_ + 2 * r2) * N_ + n0 + cg * 8];
        const float* s1 = s0 + N_;
        f0 = *(const float4*)&s0[0]; f1 = *(const float4*)&s0[4];
        g0 = *(const float4*)&s1[0]; g1 = *(const float4*)&s1[4];
    }

    for (int ks = 0; ks < 16; ++ks) {
        #pragma unroll
        for (int p = 0; p < 2; ++p)
            *(uint4*)&aA[(p * 32 + r2) * 72 + cg * 8] = aR[p];
        {
            float r0[8] = {f0.x, f0.y, f0.z, f0.w, f1.x, f1.y, f1.z, f1.w};
            float r1[8] = {g0.x, g0.y, g0.z, g0.w, g1.x, g1.y, g1.z, g1.w};
            #pragma unroll
            for (int j = 0; j < 8; ++j)
                bB32[(cg * 8 + j) * 33 + r2] = pack2(r0[j], r1[j]);
        }
        __syncthreads();
        if (ks < 15) {  // next step's loads fly across MFMA+barrier
            int k0 = (ks + 1) * 64;
            #pragma unroll
            for (int p = 0; p < 2; ++p)
                aR[p] = *(const uint4*)&efT[((size_t)b * D_ + p * 32 + r2) * E_ + k0 + cg * 8];
            const float* s0 = &H[((size_t)b * E_ + k0 + 2 * r2) * N_ + n0 + cg * 8];
            const float* s1 = s0 + N_;
            f0 = *(const float4*)&s0[0]; f1 = *(const float4*)&s0[4];
            g0 = *(const float4*)&s1[0]; g1 = *(const float4*)&s1[4];
        }
        #pragma unroll
        for (int h = 0; h < 2; ++h) {
            union { unsigned int u[4]; bf16x8 v; } bb;
            #pragma unroll
            for (int i = 0; i < 4; ++i)
                bb.u[i] = bB32[(w * 16 + c) * 33 + h * 16 + q * 4 + i];
            #pragma unroll
            for (int fm = 0; fm < 4; ++fm) {
                bf16x8 afr = *(const bf16x8*)&aA[(fm * 16 + c) * 72 + h * 32 + q * 8];
                acc[fm] = MFMA16(afr, bb.v, acc[fm]);
            }
        }
        __syncthreads();
    }
    #pragma unroll
    for (int fm = 0; fm < 4; ++fm) {
        *(f32x4*)&out[((size_t)b * N_ + n0 + w * 16 + c) * 128 + fm * 16 + q * 4] = acc[fm];
    }
}

// ---------------------------------------------------------------------------
extern "C" void kernel_launch(void* const* d_in, const int* in_sizes, int n_in,
                              void* d_out, int out_size, void* d_ws, size_t ws_size,
                              hipStream_t stream) {
    const float* ed  = (const float*)d_in[0];  // [B,E,T]
    const float* H   = (const float*)d_in[1];  // [B,E,N]
    const float* ori = (const float*)d_in[2];  // [B,N,64]
    const float* W1  = (const float*)d_in[3];  // [T,64,128]
    const float* b1  = (const float*)d_in[4];  // [T,128]
    const float* W2  = (const float*)d_in[5];  // [T,128,64]
    const float* b2  = (const float*)d_in[6];  // [T,64]
    float* out = (float*)d_out;

    char* ws = (char*)d_ws;
    unsigned short* oriT = (unsigned short*)ws; ws += (size_t)B_ * D_ * N_ * 2;    // 4 MB
    unsigned short* W1T  = (unsigned short*)ws; ws += (size_t)T_ * HID_ * D_ * 2;
    unsigned short* W2T  = (unsigned short*)ws; ws += (size_t)T_ * D_ * HID_ * 2;
    unsigned short* efT  = (unsigned short*)ws; ws += (size_t)B_ * D_ * E_ * 2;    // 8 MB

    hipLaunchKernelGGL(k_prep_w, dim3(320), dim3(256), 0, stream, W1, W2, W1T, W2T);
    hipLaunchKernelGGL(k_ori_prep, dim3(8, 64), dim3(256), 0, stream, ori, out, oriT);
    hipLaunchKernelGGL(k_edge_mlp, dim3(1024), dim3(256), 0, stream,
                       H, oriT, ed, b1, b2, W1T, W2T, efT);
    hipLaunchKernelGGL(k_gemm_out, dim3(8, 64), dim3(256), 0, stream, H, efT, out);
}